// Round 3
// baseline (367.979 us; speedup 1.0000x reference)
//
#include <hip/hip_runtime.h>
#include <hip/hip_bf16.h>
#include <stdint.h>

// dims (fixed by the problem)
#define T_TOK 4096
#define NE    8
#define DM    1024
#define FF    4096
#define CAP   1536

typedef __attribute__((ext_vector_type(8))) __bf16 bf16x8;
typedef __attribute__((ext_vector_type(4))) float  f32x4;

__device__ __forceinline__ void gload_lds16(const void* gptr, void* lptr) {
  __builtin_amdgcn_global_load_lds(
      (__attribute__((address_space(1))) void*)(uintptr_t)gptr,
      (__attribute__((address_space(3))) void*)(uintptr_t)lptr,
      16, 0, 0);
}

// ---------------- small prep kernels ----------------

__global__ void conv_x_kernel(const float4* __restrict__ src, ushort4* __restrict__ dst, int n4) {
  int i = blockIdx.x * blockDim.x + threadIdx.x;
  if (i >= n4) return;
  float4 v = src[i];
  ushort4 o;
  o.x = __builtin_bit_cast(unsigned short, __float2bfloat16(v.x));
  o.y = __builtin_bit_cast(unsigned short, __float2bfloat16(v.y));
  o.z = __builtin_bit_cast(unsigned short, __float2bfloat16(v.z));
  o.w = __builtin_bit_cast(unsigned short, __float2bfloat16(v.w));
  dst[i] = o;
}

// transpose+convert: src f32 [B][R][C] -> dst bf16 [B][C][R]
__global__ __launch_bounds__(256)
void tconv_kernel(const float* __restrict__ src, __hip_bfloat16* __restrict__ dst,
                  int R, int C) {
  __shared__ float tile[64][65];
  const int b  = blockIdx.z;
  const int r0 = blockIdx.y * 64;
  const int c0 = blockIdx.x * 64;
  const float* s = src + (size_t)b * R * C;
  __hip_bfloat16* d = dst + (size_t)b * R * C;
  const int tid = threadIdx.x;
  const int tx = tid & 63, ty = tid >> 6;
#pragma unroll
  for (int rr = ty; rr < 64; rr += 4)
    tile[rr][tx] = s[(size_t)(r0 + rr) * C + c0 + tx];
  __syncthreads();
  const int lg = tid & 15;
  const int cg = tid >> 4;
#pragma unroll
  for (int w = 0; w < 4; ++w) {
    const int cc = w * 16 + cg;
    const int r4 = lg * 4;
    ushort4 o;
    o.x = __builtin_bit_cast(unsigned short, __float2bfloat16(tile[r4 + 0][cc]));
    o.y = __builtin_bit_cast(unsigned short, __float2bfloat16(tile[r4 + 1][cc]));
    o.z = __builtin_bit_cast(unsigned short, __float2bfloat16(tile[r4 + 2][cc]));
    o.w = __builtin_bit_cast(unsigned short, __float2bfloat16(tile[r4 + 3][cc]));
    *(ushort4*)&d[(size_t)(c0 + cc) * R + r0 + r4] = o;
  }
}

__global__ void router_kernel(const float* __restrict__ rw, int* __restrict__ counts,
                              int* __restrict__ tok_ids, float* __restrict__ gains) {
  int t = blockIdx.x * blockDim.x + threadIdx.x;
  if (t >= T_TOK) return;
#pragma unroll
  for (int e = 0; e < NE; ++e) {
    float w = rw[t * NE + e];
    if (w > 0.f) {
      int pos = atomicAdd(&counts[e], 1);
      if (pos < CAP) {
        tok_ids[e * CAP + pos] = t;
        gains[e * CAP + pos]   = w;
      }
    }
  }
}

__global__ void pad_kernel(const int* __restrict__ counts, int* __restrict__ tok_ids,
                           float* __restrict__ gains) {
  int i = blockIdx.x * blockDim.x + threadIdx.x;
  if (i >= NE * CAP) return;
  int e = i / CAP, pos = i % CAP;
  int ne = min(counts[e], CAP);
  if (pos >= ne) { tok_ids[i] = 0; gains[i] = 0.f; }
}

// ---------------- 8-phase 256x256 grouped MFMA GEMM (m201-style) ----------------
// BM=BN=256, BK=64, 512 threads (8 waves, 2M x 4N), mfma 16x16x32 bf16.
// LDS 128KB: A[2dbuf][2half][128][64]bf16, B same. XOR swizzle kgran^=(row&7)
// applied on pre-swizzled GLOBAL source + on read address (both-sides involution).
// Per phase: {ds_read subtile | 1 half-tile gload prefetch | s_barrier |
// lgkmcnt(0) | sched_barrier | setprio(1) | 16 MFMA | setprio(0)}; counted
// vmcnt(4) only at phases 4 and 8 (2 half-tiles stay in flight, never drain 0).

template <int PASS>
__global__ __launch_bounds__(512, 2)
void moe_gemm8(const __hip_bfloat16* __restrict__ Asrc,
               const __hip_bfloat16* __restrict__ Bsrc,   // [E][NP][K] (B^T, k contiguous)
               const float* __restrict__ bias,            // [E][NP]
               const int* __restrict__ counts,
               const int* __restrict__ tok_ids,
               const float* __restrict__ gains,
               __hip_bfloat16* __restrict__ Hout,         // PASS1 out [E][CAP][FF]
               float* __restrict__ y)                     // PASS2 out [T][DM]
{
  constexpr int K   = (PASS == 1) ? DM : FF;
  constexpr int NP  = (PASS == 1) ? FF : DM;
  constexpr int MT  = CAP / 256;          // 6
  constexpr int NT  = NP / 256;           // 16 / 4
  constexpr int SK  = (PASS == 1) ? 1 : 2;
  constexpr int NWG = NE * MT * NT * SK;  // 768 / 384 (both %8==0)
  constexpr int KP  = K / SK;             // K per split
  constexpr int KT  = KP / 64;            // 16 / 32 K-tiles (pow2)
  constexpr int KTM = KT - 1;
  constexpr int NIT = KT / 2;

  // XCD-aware bijective swizzle (NWG % 8 == 0)
  const int id = (blockIdx.x & 7) * (NWG / 8) + (blockIdx.x >> 3);
  const int e  = id / (MT * NT * SK);
  int r        = id % (MT * NT * SK);
  const int sp = r / (MT * NT);
  r            = r % (MT * NT);
  const int nt = r / MT;     // mt fastest: same B panel reused on same XCD
  const int mt = r % MT;

  const int Ne = min(counts[e], CAP);
  const int m0 = mt * 256;
  if (m0 >= Ne) return;
  const int n0 = nt * 256;
  const int k0 = sp * KP;

  __shared__ alignas(128) char LDSmem[131072];
  char* AsB = LDSmem;            // [d][h][128 rows][128 bytes]
  char* BsB = LDSmem + 65536;

  const int tid  = threadIdx.x;
  const int lane = tid & 63;
  const int wid  = tid >> 6;
  const int wm   = wid >> 2;     // 0..1
  const int wn   = wid & 3;      // 0..3
  const int fr   = lane & 15;
  const int fq   = lane >> 4;    // 0..3

  // ---- staging (gload_lds): thread covers granule g = l*512+tid, row=g>>3, kg=g&7
  const int sr  = tid >> 3;            // row within 64-row group (both loads: row&7 == sr&7)
  const int kg  = tid & 7;
  const int ksw = ((kg ^ (sr & 7)) << 4);  // swizzled source byte offset within 128B chunk

  const char *aP[2][2], *bP[2][2];
#pragma unroll
  for (int h = 0; h < 2; ++h)
#pragma unroll
    for (int l = 0; l < 2; ++l) {
      const int row = h * 128 + l * 64 + sr;
      if (PASS == 1) {
        const int tok = tok_ids[e * CAP + m0 + row];
        aP[h][l] = (const char*)Asrc + ((size_t)tok * DM + k0) * 2 + ksw;
      } else {
        aP[h][l] = (const char*)Asrc + (((size_t)e * CAP + m0 + row) * FF + k0) * 2 + ksw;
      }
      bP[h][l] = (const char*)Bsrc + (((size_t)e * NP + n0 + row) * K + k0) * 2 + ksw;
    }

  // ---- ds_read bases (per lane); fragment row = base16 + fr -> row&7 == fr&7
  const int kz0 = ((fq ^ (fr & 7)) << 4);
  const int kz1 = (((4 + fq) ^ (fr & 7)) << 4);
  const char* rdA0 = AsB + wm * 16384 + fr * 128 + kz0;
  const char* rdA1 = AsB + wm * 16384 + fr * 128 + kz1;
  const char* rdB0 = BsB + (wn >> 1) * 16384 + (wn & 1) * 8192 + fr * 128 + kz0;
  const char* rdB1 = BsB + (wn >> 1) * 16384 + (wn & 1) * 8192 + fr * 128 + kz1;

  f32x4  acc[8][4] = {};
  bf16x8 bfr[4][2], af[2][2];

#define STAGE_A(h, d, kt) do {                                                          \
    gload_lds16(aP[h][0] + (kt) * 128, AsB + (d) * 32768 + (h) * 16384 + tid * 16);     \
    gload_lds16(aP[h][1] + (kt) * 128, AsB + (d) * 32768 + (h) * 16384 + 8192 + tid * 16); \
  } while (0)
#define STAGE_B(h, d, kt) do {                                                          \
    gload_lds16(bP[h][0] + (kt) * 128, BsB + (d) * 32768 + (h) * 16384 + tid * 16);     \
    gload_lds16(bP[h][1] + (kt) * 128, BsB + (d) * 32768 + (h) * 16384 + 8192 + tid * 16); \
  } while (0)
#define VM4 asm volatile("s_waitcnt vmcnt(4)" ::: "memory")
#define PHASE(d, q, LOADB, STG, VM) do {                                                \
    if (LOADB) {                                                                        \
      _Pragma("unroll") for (int j = 0; j < 4; ++j) {                                   \
        bfr[j][0] = *(const bf16x8*)(rdB0 + (d) * 32768 + j * 2048);                    \
        bfr[j][1] = *(const bf16x8*)(rdB1 + (d) * 32768 + j * 2048);                    \
      }                                                                                 \
    }                                                                                   \
    af[0][0] = *(const bf16x8*)(rdA0 + (d) * 32768 + (q) * 4096);                       \
    af[0][1] = *(const bf16x8*)(rdA1 + (d) * 32768 + (q) * 4096);                       \
    af[1][0] = *(const bf16x8*)(rdA0 + (d) * 32768 + (q) * 4096 + 2048);                \
    af[1][1] = *(const bf16x8*)(rdA1 + (d) * 32768 + (q) * 4096 + 2048);                \
    STG;                                                                                \
    asm volatile("s_barrier" ::: "memory");                                             \
    asm volatile("s_waitcnt lgkmcnt(0)" ::: "memory");                                  \
    __builtin_amdgcn_sched_barrier(0);                                                  \
    __builtin_amdgcn_s_setprio(1);                                                      \
    _Pragma("unroll") for (int f = 0; f < 2; ++f)                                       \
      _Pragma("unroll") for (int j = 0; j < 4; ++j) {                                   \
        acc[(q) * 2 + f][j] = __builtin_amdgcn_mfma_f32_16x16x32_bf16(                  \
            af[f][0], bfr[j][0], acc[(q) * 2 + f][j], 0, 0, 0);                         \
        acc[(q) * 2 + f][j] = __builtin_amdgcn_mfma_f32_16x16x32_bf16(                  \
            af[f][1], bfr[j][1], acc[(q) * 2 + f][j], 0, 0, 0);                         \
      }                                                                                 \
    __builtin_amdgcn_s_setprio(0);                                                      \
    __builtin_amdgcn_sched_barrier(0);                                                  \
    VM;                                                                                 \
    asm volatile("s_barrier" ::: "memory");                                             \
  } while (0)

  // prologue: tile0 -> buf0 (all), tile1 B -> buf1; keep tile1 B in flight
  STAGE_B(0, 0, 0); STAGE_B(1, 0, 0); STAGE_A(0, 0, 0); STAGE_A(1, 0, 0);
  STAGE_B(0, 1, 1); STAGE_B(1, 1, 1);
  asm volatile("s_waitcnt vmcnt(4)" ::: "memory");
  asm volatile("s_barrier" ::: "memory");

#pragma unroll 1
  for (int it = 0; it < NIT; ++it) {
    const int ta = 2 * it + 1;              // A of this iter's buf1 tile
    const int tb = (2 * it + 2) & KTM;      // next buf0 tile (wrap: harmless valid loads)
    const int tc = (2 * it + 3) & KTM;      // next buf1 tile
    PHASE(0, 0, true,  STAGE_A(0, 1, ta), (void)0);
    PHASE(0, 1, false, STAGE_A(1, 1, ta), (void)0);
    PHASE(0, 2, false, STAGE_B(0, 0, tb), (void)0);
    PHASE(0, 3, false, STAGE_B(1, 0, tb), VM4);
    PHASE(1, 0, true,  STAGE_A(0, 0, tb), (void)0);
    PHASE(1, 1, false, STAGE_A(1, 0, tb), (void)0);
    PHASE(1, 2, false, STAGE_B(0, 1, tc), (void)0);
    PHASE(1, 3, false, STAGE_B(1, 1, tc), VM4);
  }
#undef STAGE_A
#undef STAGE_B
#undef VM4
#undef PHASE

  // ---- epilogue ----
  if (PASS == 1) {
#pragma unroll
    for (int nj = 0; nj < 4; ++nj) {
      const int col = n0 + wn * 64 + nj * 16 + fr;
      const float bv = bias[e * NP + col];
#pragma unroll
      for (int mi = 0; mi < 8; ++mi)
#pragma unroll
        for (int rr = 0; rr < 4; ++rr) {
          const int row = m0 + wm * 128 + mi * 16 + fq * 4 + rr;
          float v = acc[mi][nj][rr] + bv;
          Hout[((size_t)e * CAP + row) * FF + col] = __float2bfloat16(v > 0.f ? v : 0.f);
        }
    }
  } else {
    float bv[4];
#pragma unroll
    for (int nj = 0; nj < 4; ++nj)
      bv[nj] = (sp == 0) ? bias[e * NP + n0 + wn * 64 + nj * 16 + fr] : 0.f;
#pragma unroll
    for (int mi = 0; mi < 8; ++mi)
#pragma unroll
      for (int rr = 0; rr < 4; ++rr) {
        const int row  = m0 + wm * 128 + mi * 16 + fq * 4 + rr;
        const int slot = e * CAP + row;
        const float g  = gains[slot];
        if (g != 0.f) {
          const int tok = tok_ids[slot];
          float* yrow = y + (size_t)tok * DM + n0 + wn * 64 + fr;
#pragma unroll
          for (int nj = 0; nj < 4; ++nj)
            atomicAdd(yrow + nj * 16, (acc[mi][nj][rr] + bv[nj]) * g);
        }
      }
  }
}

// ---------------- launch ----------------

extern "C" void kernel_launch(void* const* d_in, const int* in_sizes, int n_in,
                              void* d_out, int out_size, void* d_ws, size_t ws_size,
                              hipStream_t stream) {
  const float* x  = (const float*)d_in[0];
  // d_in[1] = route_mask (bool) — unused: mask == (route_weight > 0)
  const float* rw = (const float*)d_in[2];
  const float* W1 = (const float*)d_in[3];
  const float* b1 = (const float*)d_in[4];
  const float* W2 = (const float*)d_in[5];
  const float* b2 = (const float*)d_in[6];
  float* y = (float*)d_out;

  char* ws = (char*)d_ws;
  size_t off = 0;
  auto alloc = [&](size_t bytes) {
    void* p = ws + off;
    off = (off + bytes + 255) & ~(size_t)255;
    return p;
  };
  __hip_bfloat16* xb  = (__hip_bfloat16*)alloc((size_t)T_TOK * DM * 2);       // 8.4 MB
  __hip_bfloat16* w1t = (__hip_bfloat16*)alloc((size_t)NE * DM * FF * 2);     // 67 MB  [E][F][D]
  __hip_bfloat16* w2t = (__hip_bfloat16*)alloc((size_t)NE * FF * DM * 2);     // 67 MB  [E][D][F]
  __hip_bfloat16* Hb  = (__hip_bfloat16*)alloc((size_t)NE * CAP * FF * 2);    // 100 MB [E][CAP][F]
  int*   counts  = (int*)alloc(NE * sizeof(int));
  int*   tok_ids = (int*)alloc((size_t)NE * CAP * sizeof(int));
  float* gains   = (float*)alloc((size_t)NE * CAP * sizeof(float));
  (void)ws_size; (void)in_sizes; (void)n_in; (void)out_size;

  hipMemsetAsync(y, 0, (size_t)T_TOK * DM * sizeof(float), stream);
  hipMemsetAsync(counts, 0, NE * sizeof(int), stream);

  conv_x_kernel<<<(T_TOK * DM / 4 + 255) / 256, 256, 0, stream>>>(
      (const float4*)x, (ushort4*)xb, T_TOK * DM / 4);
  tconv_kernel<<<dim3(FF / 64, DM / 64, NE), 256, 0, stream>>>(W1, w1t, DM, FF);
  tconv_kernel<<<dim3(DM / 64, FF / 64, NE), 256, 0, stream>>>(W2, w2t, FF, DM);
  router_kernel<<<(T_TOK + 255) / 256, 256, 0, stream>>>(rw, counts, tok_ids, gains);
  pad_kernel<<<(NE * CAP + 255) / 256, 256, 0, stream>>>(counts, tok_ids, gains);

  moe_gemm8<1><<<NE * (CAP / 256) * (FF / 256), 512, 0, stream>>>(
      xb, w1t, b1, counts, tok_ids, gains, Hb, nullptr);
  moe_gemm8<2><<<NE * (CAP / 256) * (DM / 256) * 2, 512, 0, stream>>>(
      Hb, w2t, b2, counts, tok_ids, gains, nullptr, y);
}